// Round 10
// baseline (3624.937 us; speedup 1.0000x reference)
//
#include <hip/hip_runtime.h>

typedef __attribute__((ext_vector_type(4))) float f4v;
typedef __attribute__((ext_vector_type(8))) short s8v;

#define YPITCH 68   // shorts; 136 B row pitch -> LDS 39168 B (fits 4 blocks/CU)
#define NB 8        // batches per block
#define MROWS 136   // 8 x 17 rows
#define MT 9        // padded to 144 rows

static __device__ __forceinline__ short f2bf(float f) {
    unsigned u = __builtin_bit_cast(unsigned, f);
    unsigned r = (u + 0x7FFFu + ((u >> 16) & 1u)) >> 16;  // RNE
    return (short)r;
}

// W[3][256][256] (k,f,o) fp32  ->  Wt[3][256][256] (k,o,f) bf16, via LDS tile transpose
__global__ void wt_transpose_kernel(const float* __restrict__ W, short* __restrict__ Wt) {
    __shared__ short t[64][65];
    int k  = blockIdx.x >> 4;
    int r  = blockIdx.x & 15;
    int f0 = (r >> 2) << 6;
    int o0 = (r & 3) << 6;
    const float* Wk  = W  + k * 65536;
    short*       Wtk = Wt + k * 65536;
    #pragma unroll
    for (int e = 0; e < 16; e++) {
        int idx = e * 256 + threadIdx.x;
        int f = idx >> 6, o = idx & 63;
        t[f][o] = f2bf(Wk[(f0 + f) * 256 + o0 + o]);
    }
    __syncthreads();
    #pragma unroll
    for (int e = 0; e < 16; e++) {
        int idx = e * 256 + threadIdx.x;
        int o = idx >> 6, f = idx & 63;
        Wtk[(o0 + o) * 256 + f0 + f] = t[f][o];
    }
}

// One adjacency-row dot product; i and K compile-time constants after unroll. (R3-proven)
template<int K>
static __device__ __forceinline__ float row_sum(const float* __restrict__ adj,
                                                const float xq[17], int i) {
    float a;
    if (K == 0) {
        a = adj[i * 17 + i] * xq[i];
    } else if (K == 1) {
        a = 0.f;
        #pragma unroll
        for (int j = i + 1; j < 17; j++) a += adj[i * 17 + j] * xq[j];
    } else {
        a = 0.f;
        #pragma unroll
        for (int j = 0; j < i; j++) a += adj[i * 17 + j] * xq[j];
    }
    return a;
}

template<int K>
static __device__ __forceinline__ void agg_store(const float* __restrict__ adj,
                                                 const float xq[17], short* yb) {
    #pragma unroll
    for (int t = 0; t < 8; t++) {
        float a0 = row_sum<K>(adj, xq, 2 * t);
        float a1 = row_sum<K>(adj, xq, 2 * t + 1);
        unsigned r;
        asm("v_cvt_pk_bf16_f32 %0, %1, %2" : "=v"(r) : "v"(a0), "v"(a1));
        yb[(2 * t) * YPITCH]     = (short)(r & 0xffffu);
        yb[(2 * t + 1) * YPITCH] = (short)(r >> 16);
    }
    float a = row_sum<K>(adj, xq, 16);
    unsigned r;
    asm("v_cvt_pk_bf16_f32 %0, %1, %2" : "=v"(r) : "v"(a), "v"(a));
    yb[16 * YPITCH] = (short)(r & 0xffffu);
}

// R3 structure with M-split x N-split wave grid:
//   wave = g*4 + w;  g in {0,1}: M-tiles g0 -> mt 0..4, g1 -> mt 5..8 (m==4 skipped);
//   w in 0..3: output cols [w*64, w*64+64), nt = 0..3.
// Each af LDS read now feeds 4 MFMAs (was 2) -> per-region af traffic 147KB -> 80KB.
// Same single lgkm-only barrier per region, same Ys double-buffer, same agg.
__global__ __launch_bounds__(512, 8) void gconv_kernel(
        const float* __restrict__ x, const short* __restrict__ Wt,
        const float* __restrict__ adj, const float* __restrict__ bias,
        float* __restrict__ out) {
    __shared__ __align__(16) short Ys[2][144 * YPITCH];   // 2 x 19584 B = 39168 B

    const int tid  = threadIdx.x;
    const int wave = tid >> 6;       // 0..7
    const int lane = tid & 63;
    const int mn   = lane & 15;
    const int quad = lane >> 4;
    const int bb   = wave;           // batch for aggregation (unchanged)
    const int f    = lane;           // f-column within 64-wide chunk
    const int g    = wave >> 2;      // M-group: 0 -> mt 0..4, 1 -> mt 5..8
    const int w    = wave & 3;       // N-quarter: cols [w*64, w*64+64)

    const float* xg = x   + (size_t)blockIdx.x * (NB * 17 * 256);
    float*       og = out + (size_t)blockIdx.x * (NB * 17 * 256);

    // zero pad rows 136..143 of both buffers (one-time; covered by first barrier)
    for (int idx = tid; idx < 8 * YPITCH; idx += 512) {
        Ys[0][MROWS * YPITCH + idx] = 0;
        Ys[1][MROWS * YPITCH + idx] = 0;
    }

    f4v acc[5][4];
    #pragma unroll
    for (int nt = 0; nt < 4; nt++) {
        f4v bv = *(const f4v*)(bias + w * 64 + nt * 16 + quad * 4);
        #pragma unroll
        for (int m = 0; m < 5; m++) acc[m][nt] = bv;
    }

    int buf = 0;
    for (int fc0 = 0; fc0 < 256; fc0 += 64) {
        float xq[17];
        #pragma unroll
        for (int j = 0; j < 17; j++) xq[j] = xg[(bb * 17 + j) * 256 + fc0 + f];

        #pragma unroll
        for (int k = 0; k < 3; k++) {
            // ---- W fragments: global->reg from L2, issued before agg (latency cover) ----
            const short* Wtk = Wt + k * 65536;
            s8v wf[2][4];
            #pragma unroll
            for (int ks = 0; ks < 2; ks++)
                #pragma unroll
                for (int nt = 0; nt < 4; nt++)
                    wf[ks][nt] = *(const s8v*)(Wtk + (w * 64 + nt * 16 + mn) * 256
                                               + fc0 + ks * 32 + quad * 8);

            // ---- aggregation: batch bb, all 17 joints, fused cvt+store (R3-proven) ----
            short* yb = &Ys[buf][(bb * 17) * YPITCH + f];
            if      (k == 0) agg_store<0>(adj, xq, yb);
            else if (k == 1) agg_store<1>(adj, xq, yb);
            else             agg_store<2>(adj, xq, yb);

            // ---- one barrier per region: drain LDS writes only (no vmcnt drain) ----
            asm volatile("s_waitcnt lgkmcnt(0)" ::: "memory");
            __builtin_amdgcn_s_barrier();
            __builtin_amdgcn_sched_barrier(0);

            // ---- MFMA: A = W rows (o), B = Y rows; wave covers (g-half M) x (w-quarter N)
            __builtin_amdgcn_s_setprio(1);
            #pragma unroll
            for (int ks = 0; ks < 2; ks++) {
                const int ko = ks * 32 + quad * 8;
                #pragma unroll
                for (int m = 0; m < 5; m++) {
                    if (g == 0 || m < 4) {   // g1 has only 4 tiles (mt 5..8); wave-uniform
                        const int mt = g * 5 + m;
                        s8v af = *(const s8v*)(&Ys[buf][(mt * 16 + mn) * YPITCH + ko]);
                        #pragma unroll
                        for (int nt = 0; nt < 4; nt++)
                            acc[m][nt] = __builtin_amdgcn_mfma_f32_16x16x32_bf16(
                                wf[ks][nt], af, acc[m][nt], 0, 0, 0);
                    }
                }
            }
            __builtin_amdgcn_s_setprio(0);
            buf ^= 1;
        }
    }

    // ---- epilogue: D row = quad*4+rg = o (contiguous) -> one float4 store per tile ----
    #pragma unroll
    for (int m = 0; m < 5; m++) {
        if (g == 0 || m < 4) {
            const int r = (g * 5 + m) * 16 + mn;
            if (r < MROWS) {
                #pragma unroll
                for (int nt = 0; nt < 4; nt++)
                    *(f4v*)(og + r * 256 + w * 64 + nt * 16 + quad * 4) = acc[m][nt];
            }
        }
    }
}

extern "C" void kernel_launch(void* const* d_in, const int* in_sizes, int n_in,
                              void* d_out, int out_size, void* d_ws, size_t ws_size,
                              hipStream_t stream) {
    const float* x    = (const float*)d_in[0];
    const float* W    = (const float*)d_in[1];
    const float* adj  = (const float*)d_in[2];
    const float* bias = (const float*)d_in[3];
    float* out = (float*)d_out;
    short* Wt  = (short*)d_ws;  // 3*256*256 bf16 = 393216 B

    hipLaunchKernelGGL(wt_transpose_kernel, dim3(48), dim3(256), 0, stream, W, Wt);
    hipLaunchKernelGGL(gconv_kernel, dim3(16384 / NB), dim3(512), 0, stream,
                       x, Wt, adj, bias, out);
}

// Round 11
// 1153.309 us; speedup vs baseline: 3.1431x; 3.1431x over previous
//
#include <hip/hip_runtime.h>

typedef __attribute__((ext_vector_type(4))) float f4v;
typedef __attribute__((ext_vector_type(8))) short s8v;

#define YPITCH 72   // shorts; 144 B row pitch (R3-proven)
#define NB 8        // batches per block
#define MROWS 136   // 8 x 17 rows
#define MT 9        // padded to 144 rows

static __device__ __forceinline__ short f2bf(float f) {
    unsigned u = __builtin_bit_cast(unsigned, f);
    unsigned r = (u + 0x7FFFu + ((u >> 16) & 1u)) >> 16;  // RNE
    return (short)r;
}

// W[3][256][256] (k,f,o) fp32  ->  Wt[3][256][256] (k,o,f) bf16, via LDS tile transpose
__global__ void wt_transpose_kernel(const float* __restrict__ W, short* __restrict__ Wt) {
    __shared__ short t[64][65];
    int k  = blockIdx.x >> 4;
    int r  = blockIdx.x & 15;
    int f0 = (r >> 2) << 6;
    int o0 = (r & 3) << 6;
    const float* Wk  = W  + k * 65536;
    short*       Wtk = Wt + k * 65536;
    #pragma unroll
    for (int e = 0; e < 16; e++) {
        int idx = e * 256 + threadIdx.x;
        int f = idx >> 6, o = idx & 63;
        t[f][o] = f2bf(Wk[(f0 + f) * 256 + o0 + o]);
    }
    __syncthreads();
    #pragma unroll
    for (int e = 0; e < 16; e++) {
        int idx = e * 256 + threadIdx.x;
        int o = idx >> 6, f = idx & 63;
        Wtk[(o0 + o) * 256 + f0 + f] = t[f][o];
    }
}

// One adjacency-row dot product; i and K compile-time constants after unroll. (R3-proven)
template<int K>
static __device__ __forceinline__ float row_sum(const float* __restrict__ adj,
                                                const float xq[17], int i) {
    float a;
    if (K == 0) {
        a = adj[i * 17 + i] * xq[i];
    } else if (K == 1) {
        a = 0.f;
        #pragma unroll
        for (int j = i + 1; j < 17; j++) a += adj[i * 17 + j] * xq[j];
    } else {
        a = 0.f;
        #pragma unroll
        for (int j = 0; j < i; j++) a += adj[i * 17 + j] * xq[j];
    }
    return a;
}

template<int K>
static __device__ __forceinline__ void agg_store(const float* __restrict__ adj,
                                                 const float xq[17], short* yb) {
    #pragma unroll
    for (int t = 0; t < 8; t++) {
        float a0 = row_sum<K>(adj, xq, 2 * t);
        float a1 = row_sum<K>(adj, xq, 2 * t + 1);
        unsigned r;
        asm("v_cvt_pk_bf16_f32 %0, %1, %2" : "=v"(r) : "v"(a0), "v"(a1));
        yb[(2 * t) * YPITCH]     = (short)(r & 0xffffu);
        yb[(2 * t + 1) * YPITCH] = (short)(r >> 16);
    }
    float a = row_sum<K>(adj, xq, 16);
    unsigned r;
    asm("v_cvt_pk_bf16_f32 %0, %1, %2" : "=v"(r) : "v"(a), "v"(a));
    yb[16 * YPITCH] = (short)(r & 0xffffu);
}

// R3 structure + M/N wave grid: wave = g*4 + w.
//   g in {0,1}: M-tiles g0 -> mt 0..4, g1 -> mt 5..8 (5th slot unused);
//   w in 0..3: output cols [w*64, w*64+64), nt = 0..3.
// Each af LDS read feeds 4 MFMAs (was 2): per-region af traffic 147 KB -> ~80 KB.
// __launch_bounds__(512,4): unified reg budget 128... allocator settles at 3 waves/SIMD
// (same as R3's 136-reg point). R10's (512,8) spill trap avoided.
__global__ __launch_bounds__(512, 4) void gconv_kernel(
        const float* __restrict__ x, const short* __restrict__ Wt,
        const float* __restrict__ adj, const float* __restrict__ bias,
        float* __restrict__ out) {
    __shared__ __align__(16) short Ys[2][144 * YPITCH];   // 2 x 20736 B = 41472 B

    const int tid  = threadIdx.x;
    const int wave = tid >> 6;       // 0..7
    const int lane = tid & 63;
    const int mn   = lane & 15;
    const int quad = lane >> 4;
    const int bb   = wave;           // batch for aggregation (unchanged from R3)
    const int f    = lane;           // f-column within 64-wide chunk
    const int g    = wave >> 2;      // M-group: 0 -> mt 0..4, 1 -> mt 5..8
    const int w    = wave & 3;       // N-quarter: cols [w*64, w*64+64)

    const float* xg = x   + (size_t)blockIdx.x * (NB * 17 * 256);
    float*       og = out + (size_t)blockIdx.x * (NB * 17 * 256);

    // zero pad rows 136..143 of both buffers (one-time; covered by first barrier)
    for (int idx = tid; idx < 8 * YPITCH; idx += 512) {
        Ys[0][MROWS * YPITCH + idx] = 0;
        Ys[1][MROWS * YPITCH + idx] = 0;
    }

    f4v acc[5][4];
    #pragma unroll
    for (int nt = 0; nt < 4; nt++) {
        f4v bv = *(const f4v*)(bias + w * 64 + nt * 16 + quad * 4);
        #pragma unroll
        for (int m = 0; m < 5; m++) acc[m][nt] = bv;
    }

    int buf = 0;
    for (int fc0 = 0; fc0 < 256; fc0 += 64) {
        float xq[17];
        #pragma unroll
        for (int j = 0; j < 17; j++) xq[j] = xg[(bb * 17 + j) * 256 + fc0 + f];

        #pragma unroll
        for (int k = 0; k < 3; k++) {
            // ---- W fragments: global->reg from L2, issued before agg (latency cover) ----
            const short* Wtk = Wt + k * 65536;
            s8v wf[2][4];
            #pragma unroll
            for (int ks = 0; ks < 2; ks++)
                #pragma unroll
                for (int nt = 0; nt < 4; nt++)
                    wf[ks][nt] = *(const s8v*)(Wtk + (w * 64 + nt * 16 + mn) * 256
                                               + fc0 + ks * 32 + quad * 8);

            // ---- aggregation: batch bb, all 17 joints, fused cvt+store (R3-proven) ----
            short* yb = &Ys[buf][(bb * 17) * YPITCH + f];
            if      (k == 0) agg_store<0>(adj, xq, yb);
            else if (k == 1) agg_store<1>(adj, xq, yb);
            else             agg_store<2>(adj, xq, yb);

            // ---- one barrier per k-step: drain LDS writes only (no vmcnt drain) ----
            asm volatile("s_waitcnt lgkmcnt(0)" ::: "memory");
            __builtin_amdgcn_s_barrier();
            __builtin_amdgcn_sched_barrier(0);

            // ---- MFMA: wave covers (g-half of M) x (w-quarter of N) ----
            __builtin_amdgcn_s_setprio(1);
            #pragma unroll
            for (int ks = 0; ks < 2; ks++) {
                const int ko = ks * 32 + quad * 8;
                #pragma unroll
                for (int m = 0; m < 5; m++) {
                    if (g == 0 || m < 4) {   // wave-uniform: g1 covers 4 tiles
                        const int mt = g * 5 + m;
                        s8v af = *(const s8v*)(&Ys[buf][(mt * 16 + mn) * YPITCH + ko]);
                        #pragma unroll
                        for (int nt = 0; nt < 4; nt++)
                            acc[m][nt] = __builtin_amdgcn_mfma_f32_16x16x32_bf16(
                                wf[ks][nt], af, acc[m][nt], 0, 0, 0);
                    }
                }
            }
            __builtin_amdgcn_s_setprio(0);
            buf ^= 1;
        }
    }

    // ---- epilogue: D row = quad*4+rg = o (contiguous) -> one float4 store per tile ----
    #pragma unroll
    for (int m = 0; m < 5; m++) {
        if (g == 0 || m < 4) {
            const int r = (g * 5 + m) * 16 + mn;
            if (r < MROWS) {
                #pragma unroll
                for (int nt = 0; nt < 4; nt++)
                    *(f4v*)(og + r * 256 + w * 64 + nt * 16 + quad * 4) = acc[m][nt];
            }
        }
    }
}

extern "C" void kernel_launch(void* const* d_in, const int* in_sizes, int n_in,
                              void* d_out, int out_size, void* d_ws, size_t ws_size,
                              hipStream_t stream) {
    const float* x    = (const float*)d_in[0];
    const float* W    = (const float*)d_in[1];
    const float* adj  = (const float*)d_in[2];
    const float* bias = (const float*)d_in[3];
    float* out = (float*)d_out;
    short* Wt  = (short*)d_ws;  // 3*256*256 bf16 = 393216 B

    hipLaunchKernelGGL(wt_transpose_kernel, dim3(48), dim3(256), 0, stream, W, Wt);
    hipLaunchKernelGGL(gconv_kernel, dim3(16384 / NB), dim3(512), 0, stream,
                       x, Wt, adj, bias, out);
}